// Round 3
// baseline (192.805 us; speedup 1.0000x reference)
//
#include <hip/hip_runtime.h>
#include <math.h>

#define K_CB 1024
#define D_Z  64
#define MT   16
#define NTOT 65536
#define NBLK (NTOT / MT)

typedef __attribute__((ext_vector_type(8))) short  s16x8;
typedef __attribute__((ext_vector_type(4))) short  s16x4;
typedef __attribute__((ext_vector_type(4))) float  f32x4;

// ws layout (bytes)
#define WS_CB16  0        // [1024][64] bf16
#define WS_CBT16 131072   // [64][1024] bf16
#define WS_NWSQC 262144   // [1024] f32  (-w*||c||^2)
#define WS_PART  266240   // [4096] f32 block partials

__device__ __forceinline__ unsigned short f2b(float f) {
  unsigned int u = __float_as_uint(f);
  u += 0x7fffu + ((u >> 16) & 1u);
  return (unsigned short)(u >> 16);
}

__global__ void vq_prep(const float* __restrict__ cb, const float* __restrict__ lvq,
                        unsigned char* __restrict__ wsb) {
  unsigned short* cb16  = (unsigned short*)(wsb + WS_CB16);
  unsigned short* cbT16 = (unsigned short*)(wsb + WS_CBT16);
  float* nwsqc = (float*)(wsb + WS_NWSQC);
  const float w = 0.5f / fmaxf(1.0f + __expf(lvq[0]), 1e-10f);
  const int tid = threadIdx.x;
  const int k  = blockIdx.x * 16 + (tid >> 4);
  const int d0 = (tid & 15) * 4;
  const f32x4 v = *(const f32x4*)(cb + k * D_Z + d0);
  s16x4 b4;
  #pragma unroll
  for (int i = 0; i < 4; i++) b4[i] = (short)f2b(v[i]);
  *(s16x4*)(cb16 + k * D_Z + d0) = b4;
  #pragma unroll
  for (int i = 0; i < 4; i++) cbT16[(d0 + i) * K_CB + k] = (unsigned short)b4[i];
  float s = v[0]*v[0] + v[1]*v[1] + v[2]*v[2] + v[3]*v[3];
  #pragma unroll
  for (int off = 1; off < 16; off <<= 1) s += __shfl_xor(s, off);
  if ((tid & 15) == 0) nwsqc[k] = -w * s;
}

#define NTLD(p) __builtin_nontemporal_load((const f32x4*)(p))

__global__ __launch_bounds__(256, 4)
void vq_main(const float* __restrict__ x, const float* __restrict__ gum,
             const float* __restrict__ lvq, unsigned char* __restrict__ wsb,
             float* __restrict__ out) {
  __shared__ __align__(16) unsigned short xa[1024];      // x bf16 frag-linear
  __shared__ __align__(16) unsigned short es[MT][1032];  // encodings bf16 (per-wave baseline)
  __shared__ __align__(16) float pstat[4][MT][4];        // m1,s1,A,m2 per wave
  __shared__ __align__(16) float s2p[4][MT];
  __shared__ float kldrow[MT];
  __shared__ float wred[4];

  const int tid  = threadIdx.x;
  const int wv   = tid >> 6;
  const int lane = tid & 63;
  const int m16  = lane & 15;
  const int g    = lane >> 4;
  const int blk  = blockIdx.x;
  const int row0 = blk * MT;
  const int bidx = row0 >> 10;
  const int rem0 = row0 & 1023;

  const float w  = 0.5f / fmaxf(1.0f + __expf(lvq[0]), 1e-10f);
  const float w2 = 2.0f * w;

  const unsigned short* cb16  = (const unsigned short*)(wsb + WS_CB16);
  const unsigned short* cbT16 = (const unsigned short*)(wsb + WS_CBT16);
  const float* nwsqc = (const float*)(wsb + WS_NWSQC);

  // ---- P0: stage x tile (bf16 MFMA-frag layout) ----
  {
    const int m = tid & 15, db = tid >> 4;
    #pragma unroll
    for (int i = 0; i < 4; i++) {
      const int d = db + 16 * i;
      const float v = x[((bidx * D_Z + d) << 10) + rem0 + m];
      xa[(d >> 5) * 512 + ((d >> 3) & 3) * 128 + m * 8 + (d & 7)] = f2b(v);
    }
  }
  __syncthreads();

  // ---- GEMM1 (swapped): D[code][m]; chunk-of-2 codes, distance-1 prefetch ----
  f32x4 acc[16];
  #pragma unroll
  for (int t = 0; t < 16; t++) acc[t] = (f32x4){0.f, 0.f, 0.f, 0.f};
  {
    const s16x8 xb0 = *(const s16x8*)(xa + g * 128 + m16 * 8);
    const s16x8 xb1 = *(const s16x8*)(xa + 512 + g * 128 + m16 * 8);
    const unsigned short* ap = cb16 + (wv * 256 + m16) * D_Z + g * 8;
    s16x8 c0a = *(const s16x8*)(ap);
    s16x8 c0b = *(const s16x8*)(ap + 32);
    s16x8 c1a = *(const s16x8*)(ap + 1024);
    s16x8 c1b = *(const s16x8*)(ap + 1024 + 32);
    #pragma unroll
    for (int c = 0; c < 8; c++) {
      s16x8 n0a = c0a, n0b = c0b, n1a = c1a, n1b = c1b;
      if (c < 7) {
        const unsigned short* np = ap + (2 * c + 2) * 1024;
        n0a = *(const s16x8*)(np);
        n0b = *(const s16x8*)(np + 32);
        n1a = *(const s16x8*)(np + 1024);
        n1b = *(const s16x8*)(np + 1024 + 32);
      }
      acc[2*c]   = __builtin_amdgcn_mfma_f32_16x16x32_bf16(c0a, xb0, acc[2*c],   0, 0, 0);
      acc[2*c]   = __builtin_amdgcn_mfma_f32_16x16x32_bf16(c0b, xb1, acc[2*c],   0, 0, 0);
      acc[2*c+1] = __builtin_amdgcn_mfma_f32_16x16x32_bf16(c1a, xb0, acc[2*c+1], 0, 0, 0);
      acc[2*c+1] = __builtin_amdgcn_mfma_f32_16x16x32_bf16(c1b, xb1, acc[2*c+1], 0, 0, 0);
      c0a = n0a; c0b = n0b; c1a = n1a; c1b = n1b;
    }
  }

  // ---- issue first 8 gumbel loads; latency hidden under softmax stats ----
  const float* gp = gum + (row0 + m16) * K_CB + wv * 256 + g * 4;
  f32x4 ga0 = NTLD(gp +   0), ga1 = NTLD(gp +  16), ga2 = NTLD(gp +  32), ga3 = NTLD(gp +  48);
  f32x4 gb0 = NTLD(gp +  64), gb1 = NTLD(gp +  80), gb2 = NTLD(gp +  96), gb3 = NTLD(gp + 112);

  // ---- P2/P3: logits (row-shifted) + probs stats ----
  float m1 = -3.4e38f;
  #pragma unroll
  for (int t = 0; t < 16; t++) {
    const f32x4 sc = *(const f32x4*)(nwsqc + wv * 256 + t * 16 + g * 4);
    #pragma unroll
    for (int r = 0; r < 4; r++) {
      acc[t][r] = fmaf(w2, acc[t][r], sc[r]);
      m1 = fmaxf(m1, acc[t][r]);
    }
  }
  m1 = fmaxf(m1, __shfl_xor(m1, 16));
  m1 = fmaxf(m1, __shfl_xor(m1, 32));
  float s1 = 0.f, Aa = 0.f;
  #pragma unroll
  for (int t = 0; t < 16; t++) {
    #pragma unroll
    for (int r = 0; r < 4; r++) {
      const float u = acc[t][r] - m1;
      const float e = __expf(u);
      s1 += e;
      Aa = fmaf(u, e, Aa);
    }
  }
  s1 += __shfl_xor(s1, 16); s1 += __shfl_xor(s1, 32);
  Aa += __shfl_xor(Aa, 16); Aa += __shfl_xor(Aa, 32);

  // ---- P4: z = (logit+g)/T with chunked prefetch; per-wave m2 ----
  float m2 = -3.4e38f;
  #define PROCG(gv, t) { _Pragma("unroll") \
    for (int r = 0; r < 4; r++) { \
      const float z = 2.0f * (acc[t][r] + gv[r]); \
      acc[t][r] = z; m2 = fmaxf(m2, z); } }
  PROCG(ga0, 0) PROCG(ga1, 1) PROCG(ga2, 2) PROCG(ga3, 3)
  ga0 = NTLD(gp + 128); ga1 = NTLD(gp + 144); ga2 = NTLD(gp + 160); ga3 = NTLD(gp + 176);
  PROCG(gb0, 4) PROCG(gb1, 5) PROCG(gb2, 6) PROCG(gb3, 7)
  gb0 = NTLD(gp + 192); gb1 = NTLD(gp + 208); gb2 = NTLD(gp + 224); gb3 = NTLD(gp + 240);
  PROCG(ga0,  8) PROCG(ga1,  9) PROCG(ga2, 10) PROCG(ga3, 11)
  PROCG(gb0, 12) PROCG(gb1, 13) PROCG(gb2, 14) PROCG(gb3, 15)
  m2 = fmaxf(m2, __shfl_xor(m2, 16));
  m2 = fmaxf(m2, __shfl_xor(m2, 32));
  if (g == 0) {
    pstat[wv][m16][0] = m1; pstat[wv][m16][1] = s1;
    pstat[wv][m16][2] = Aa; pstat[wv][m16][3] = m2;
  }

  // ---- P6': encodings e' = exp(z - m2_wv) (per-wave baseline), bf16 -> LDS ----
  float s2 = 0.f;
  #pragma unroll
  for (int t = 0; t < 16; t++) {
    s16x4 ev;
    #pragma unroll
    for (int r = 0; r < 4; r++) {
      const float e = __expf(acc[t][r] - m2);
      s2 += e;
      ev[r] = (short)f2b(e);
    }
    *(s16x4*)&es[m16][wv * 256 + t * 16 + g * 4] = ev;
  }
  s2 += __shfl_xor(s2, 16); s2 += __shfl_xor(s2, 32);
  if (g == 0) s2p[wv][m16] = s2;
  __syncthreads();

  // ---- P5: cross-wave merge; per-row block scales c_b = exp(m2_b - M2) ----
  float cs0, cs1, cs2, cs3, inv2;
  {
    f32x4 pw[4];
    float M1 = -3.4e38f, M2 = -3.4e38f;
    #pragma unroll
    for (int q = 0; q < 4; q++) {
      pw[q] = *(const f32x4*)&pstat[q][m16][0];
      M1 = fmaxf(M1, pw[q][0]);
      M2 = fmaxf(M2, pw[q][3]);
    }
    float s1g = 0.f, Ag = 0.f, s2g = 0.f, csv[4];
    #pragma unroll
    for (int q = 0; q < 4; q++) {
      const float dm = pw[q][0] - M1;
      const float c  = __expf(dm);
      s1g += c * pw[q][1];
      Ag = fmaf(c, fmaf(dm, pw[q][1], pw[q][2]), Ag);
      const float c2 = __expf(pw[q][3] - M2);
      csv[q] = c2;
      s2g = fmaf(c2, s2p[q][m16], s2g);
    }
    cs0 = csv[0]; cs1 = csv[1]; cs2 = csv[2]; cs3 = csv[3];
    inv2 = 1.0f / s2g;
    if (tid < 16) kldrow[m16] = Ag / s1g - __logf(s1g);
  }

  // ---- GEMM2 (swapped): per-source-block accumulators, scaled merge ----
  float qt0 = 0.f, qt1 = 0.f, qt2 = 0.f, qt3 = 0.f;
  {
    const unsigned short* a2p = cbT16 + (wv * 16 + m16) * K_CB + g * 8;
    const unsigned short* b2p = &es[m16][g * 8];
    const float csa[4] = {cs0, cs1, cs2, cs3};
    #pragma unroll
    for (int b = 0; b < 4; b++) {
      f32x4 qa = (f32x4){0.f, 0.f, 0.f, 0.f};
      #pragma unroll
      for (int kc = 0; kc < 8; kc++) {
        const int kk = b * 8 + kc;
        const s16x8 a2 = *(const s16x8*)(a2p + kk * 32);
        const s16x8 b2 = *(const s16x8*)(b2p + kk * 32);
        qa = __builtin_amdgcn_mfma_f32_16x16x32_bf16(a2, b2, qa, 0, 0, 0);
      }
      qt0 = fmaf(csa[b], qa[0], qt0);
      qt1 = fmaf(csa[b], qa[1], qt1);
      qt2 = fmaf(csa[b], qa[2], qt2);
      qt3 = fmaf(csa[b], qa[3], qt3);
    }
  }

  // ---- P9: normalize, write (d-major coalesced), kld_continuous ----
  float kca = 0.f;
  {
    const float qv[4] = {qt0 * inv2, qt1 * inv2, qt2 * inv2, qt3 * inv2};
    #pragma unroll
    for (int r = 0; r < 4; r++) {
      const int d = wv * 16 + g * 4 + r;
      const int off = ((bidx * D_Z + d) << 10) + rem0 + m16;
      const float xv = x[off];
      __builtin_nontemporal_store(qv[r], out + off);
      const float dx = xv - qv[r];
      kca = fmaf(dx, dx, kca);
    }
  }
  #pragma unroll
  for (int off = 1; off < 64; off <<= 1) kca += __shfl_xor(kca, off);
  if (lane == 0) wred[wv] = kca;
  __syncthreads();
  if (tid == 0) {
    float tot = w * (wred[0] + wred[1] + wred[2] + wred[3]);
    #pragma unroll
    for (int i = 0; i < MT; i++) tot += kldrow[i];
    ((float*)(wsb + WS_PART))[blk] = tot;
  }
}

__global__ void vq_reduce(const unsigned char* __restrict__ wsb, float* __restrict__ out) {
  __shared__ float red[256];
  const float* part = (const float*)(wsb + WS_PART);
  const int t = threadIdx.x;
  float s = 0.f;
  for (int i = t; i < NBLK; i += 256) s += part[i];
  red[t] = s;
  __syncthreads();
  for (int st = 128; st > 0; st >>= 1) {
    if (t < st) red[t] += red[t + st];
    __syncthreads();
  }
  if (t == 0) out[NTOT * D_Z] = red[0] * (1.0f / 64.0f);
}

extern "C" void kernel_launch(void* const* d_in, const int* in_sizes, int n_in,
                              void* d_out, int out_size, void* d_ws, size_t ws_size,
                              hipStream_t stream) {
  const float* x   = (const float*)d_in[0];
  const float* cb  = (const float*)d_in[1];
  const float* lvq = (const float*)d_in[2];
  const float* gum = (const float*)d_in[3];
  float* out = (float*)d_out;
  unsigned char* wsb = (unsigned char*)d_ws;

  hipLaunchKernelGGL(vq_prep,   dim3(64),   dim3(256), 0, stream, cb, lvq, wsb);
  hipLaunchKernelGGL(vq_main,   dim3(NBLK), dim3(256), 0, stream, x, gum, lvq, wsb, out);
  hipLaunchKernelGGL(vq_reduce, dim3(1),    dim3(256), 0, stream, wsb, out);
}

// Round 4
// 170.589 us; speedup vs baseline: 1.1302x; 1.1302x over previous
//
#include <hip/hip_runtime.h>
#include <math.h>

#define K_CB 1024
#define D_Z  64
#define MT   16
#define NTOT 65536
#define NBLK (NTOT / MT)

typedef __attribute__((ext_vector_type(8))) short  s16x8;
typedef __attribute__((ext_vector_type(4))) short  s16x4;
typedef __attribute__((ext_vector_type(4))) float  f32x4;

typedef __attribute__((address_space(1))) const unsigned char gu8;
typedef __attribute__((address_space(3))) unsigned char lu8;

// ws layout (bytes)
#define WS_CB16  0        // [1024][64] bf16
#define WS_CBT16 131072   // [64][1024] bf16
#define WS_NWSQC 262144   // [1024] f32  (-w*||c||^2)
#define WS_PART  266240   // [4096] f32 block partials

__device__ __forceinline__ unsigned short f2b(float f) {
  unsigned int u = __float_as_uint(f);
  u += 0x7fffu + ((u >> 16) & 1u);
  return (unsigned short)(u >> 16);
}

__global__ void vq_prep(const float* __restrict__ cb, const float* __restrict__ lvq,
                        unsigned char* __restrict__ wsb) {
  unsigned short* cb16  = (unsigned short*)(wsb + WS_CB16);
  unsigned short* cbT16 = (unsigned short*)(wsb + WS_CBT16);
  float* nwsqc = (float*)(wsb + WS_NWSQC);
  const float w = 0.5f / fmaxf(1.0f + __expf(lvq[0]), 1e-10f);
  const int tid = threadIdx.x;
  const int k  = blockIdx.x * 16 + (tid >> 4);
  const int d0 = (tid & 15) * 4;
  const f32x4 v = *(const f32x4*)(cb + k * D_Z + d0);
  s16x4 b4;
  #pragma unroll
  for (int i = 0; i < 4; i++) b4[i] = (short)f2b(v[i]);
  *(s16x4*)(cb16 + k * D_Z + d0) = b4;
  #pragma unroll
  for (int i = 0; i < 4; i++) cbT16[(d0 + i) * K_CB + k] = (unsigned short)b4[i];
  float s = v[0]*v[0] + v[1]*v[1] + v[2]*v[2] + v[3]*v[3];
  #pragma unroll
  for (int off = 1; off < 16; off <<= 1) s += __shfl_xor(s, off);
  if ((tid & 15) == 0) nwsqc[k] = -w * s;
}

__global__ __launch_bounds__(256, 3)
void vq_main(const float* __restrict__ x, const float* __restrict__ gum,
             const float* __restrict__ lvq, unsigned char* __restrict__ wsb,
             float* __restrict__ out) {
  __shared__ __align__(16) unsigned short xa[1024];      // x bf16 frag-linear
  __shared__ __align__(16) unsigned short es[MT][1032];  // encodings bf16
  __shared__ __align__(16) float stg[2][2048];           // gumbel chunks [16 rows][128 codes] swz
  __shared__ __align__(16) float pstat[4][MT][4];        // m1,s1,A per wave
  __shared__ __align__(16) float s2p[4][MT];
  __shared__ float m2p[4][MT];
  __shared__ float kldrow[MT];
  __shared__ float wred[4];

  const int tid  = threadIdx.x;
  const int wv   = tid >> 6;
  const int lane = tid & 63;
  const int m16  = lane & 15;
  const int g    = lane >> 4;
  const int bid  = blockIdx.x;
  const int blk  = ((bid & 7) << 9) | (bid >> 3);   // XCD-contiguous remap (bijective)
  const int row0 = blk * MT;
  const int bidx = row0 >> 10;
  const int rem0 = row0 & 1023;

  const float w  = 0.5f / fmaxf(1.0f + __expf(lvq[0]), 1e-10f);
  const float w2 = 2.0f * w;

  const unsigned short* cb16  = (const unsigned short*)(wsb + WS_CB16);
  const unsigned short* cbT16 = (const unsigned short*)(wsb + WS_CBT16);
  const float* nwsqc = (const float*)(wsb + WS_NWSQC);

  // ---- P0: stage x tile (bf16 MFMA-frag layout) ----
  {
    const int m = tid & 15, db = tid >> 4;
    #pragma unroll
    for (int i = 0; i < 4; i++) {
      const int d = db + 16 * i;
      const float v = x[((bidx * D_Z + d) << 10) + rem0 + m];
      xa[(d >> 5) * 512 + ((d >> 3) & 3) * 128 + m * 8 + (d & 7)] = f2b(v);
    }
  }
  __syncthreads();

  // ---- gumbel chunk staging: chunk c = global codes [c*128, +128), layout
  // [16 rows][512B], byte swizzle ^((row&7)<<4) done by pre-swizzling SRC.
  auto STAGE = [&](int c, int buf) {
    #pragma unroll
    for (int s = 0; s < 2; s++) {
      const int k = (wv << 1) + s;                 // instr 0..7 covers rows 2k,2k+1
      const int r = (k << 1) + (lane >> 5);
      const gu8* src = (gu8*)((const unsigned char*)gum +
          (((size_t)(row0 + r)) << 12) + (c << 9) + (((lane & 31) ^ (r & 7)) << 4));
      lu8* dst = (lu8*)((unsigned char*)&stg[buf][0] + (k << 10));
      __builtin_amdgcn_global_load_lds(src, dst, 16, 0, 0);
    }
  };
  STAGE(0, 0);
  STAGE(1, 1);

  // ---- GEMM1 (swapped): wave wv owns tiles T=4i+wv (codes (4i+wv)*16..+16) ----
  f32x4 acc[16];
  #pragma unroll
  for (int t = 0; t < 16; t++) acc[t] = (f32x4){0.f, 0.f, 0.f, 0.f};
  {
    const s16x8 xb0 = *(const s16x8*)(xa + g * 128 + m16 * 8);
    const s16x8 xb1 = *(const s16x8*)(xa + 512 + g * 128 + m16 * 8);
    const unsigned short* ap = cb16 + (wv * 16 + m16) * D_Z + g * 8;  // tile stride 4096
    s16x8 c0a = *(const s16x8*)(ap);
    s16x8 c0b = *(const s16x8*)(ap + 32);
    s16x8 c1a = *(const s16x8*)(ap + 4096);
    s16x8 c1b = *(const s16x8*)(ap + 4096 + 32);
    #pragma unroll
    for (int cp = 0; cp < 8; cp++) {
      s16x8 n0a = c0a, n0b = c0b, n1a = c1a, n1b = c1b;
      if (cp < 7) {
        const unsigned short* np = ap + (2 * cp + 2) * 4096;
        n0a = *(const s16x8*)(np);
        n0b = *(const s16x8*)(np + 32);
        n1a = *(const s16x8*)(np + 4096);
        n1b = *(const s16x8*)(np + 4096 + 32);
      }
      acc[2*cp]   = __builtin_amdgcn_mfma_f32_16x16x32_bf16(c0a, xb0, acc[2*cp],   0, 0, 0);
      acc[2*cp]   = __builtin_amdgcn_mfma_f32_16x16x32_bf16(c0b, xb1, acc[2*cp],   0, 0, 0);
      acc[2*cp+1] = __builtin_amdgcn_mfma_f32_16x16x32_bf16(c1a, xb0, acc[2*cp+1], 0, 0, 0);
      acc[2*cp+1] = __builtin_amdgcn_mfma_f32_16x16x32_bf16(c1b, xb1, acc[2*cp+1], 0, 0, 0);
      c0a = n0a; c0b = n0b; c1a = n1a; c1b = n1b;
    }
  }

  // ---- logits + probs stats (before gumbel loop) ----
  float m1 = -3.4e38f;
  #pragma unroll
  for (int t = 0; t < 16; t++) {
    const f32x4 sc = *(const f32x4*)(nwsqc + t * 64 + wv * 16 + g * 4);
    #pragma unroll
    for (int r = 0; r < 4; r++) {
      acc[t][r] = fmaf(w2, acc[t][r], sc[r]);
      m1 = fmaxf(m1, acc[t][r]);
    }
  }
  m1 = fmaxf(m1, __shfl_xor(m1, 16));
  m1 = fmaxf(m1, __shfl_xor(m1, 32));
  float s1 = 0.f, Aa = 0.f;
  #pragma unroll
  for (int t = 0; t < 16; t++) {
    #pragma unroll
    for (int r = 0; r < 4; r++) {
      const float u = acc[t][r] - m1;
      const float e = __expf(u);
      s1 += e;
      Aa = fmaf(u, e, Aa);
    }
  }
  s1 += __shfl_xor(s1, 16); s1 += __shfl_xor(s1, 32);
  Aa += __shfl_xor(Aa, 16); Aa += __shfl_xor(Aa, 32);
  if (g == 0) {
    pstat[wv][m16][0] = m1; pstat[wv][m16][1] = s1; pstat[wv][m16][2] = Aa;
  }

  // ---- chunked gumbel pipeline: z = 2*(logit+g), per-wave m2 ----
  float m2 = -3.4e38f;
  #pragma unroll
  for (int c = 0; c < 8; c++) {
    if (c < 7) { asm volatile("s_waitcnt vmcnt(2)" ::: "memory"); }
    else       { asm volatile("s_waitcnt vmcnt(0)" ::: "memory"); }
    __builtin_amdgcn_s_barrier();
    __builtin_amdgcn_sched_barrier(0);
    const unsigned char* bp = (const unsigned char*)&stg[c & 1][0];
    #pragma unroll
    for (int h = 0; h < 2; h++) {
      const int i = (c << 1) + h;
      const f32x4 gv = *(const f32x4*)(bp + (m16 << 9) +
                        ((((h << 4) + (wv << 2) + g) ^ (m16 & 7)) << 4));
      #pragma unroll
      for (int r = 0; r < 4; r++) {
        const float z = 2.0f * (acc[i][r] + gv[r]);
        acc[i][r] = z;
        m2 = fmaxf(m2, z);
      }
    }
    asm volatile("s_waitcnt lgkmcnt(0)" ::: "memory");
    __builtin_amdgcn_sched_barrier(0);
    __builtin_amdgcn_s_barrier();
    if (c < 6) STAGE(c + 2, c & 1);
  }

  // ---- m2 merge to row-global M2 ----
  m2 = fmaxf(m2, __shfl_xor(m2, 16));
  m2 = fmaxf(m2, __shfl_xor(m2, 32));
  if (g == 0) m2p[wv][m16] = m2;
  __syncthreads();
  const float M2 = fmaxf(fmaxf(m2p[0][m16], m2p[1][m16]),
                         fmaxf(m2p[2][m16], m2p[3][m16]));
  if (tid < 16) {
    float M1 = -3.4e38f;
    f32x4 pw[4];
    #pragma unroll
    for (int q = 0; q < 4; q++) {
      pw[q] = *(const f32x4*)&pstat[q][tid][0];
      M1 = fmaxf(M1, pw[q][0]);
    }
    float s1g = 0.f, Ag = 0.f;
    #pragma unroll
    for (int q = 0; q < 4; q++) {
      const float dm = pw[q][0] - M1;
      const float cc = __expf(dm);
      s1g += cc * pw[q][1];
      Ag = fmaf(cc, fmaf(dm, pw[q][1], pw[q][2]), Ag);
    }
    kldrow[tid] = Ag / s1g - __logf(s1g);
  }

  // ---- encodings e = exp(z - M2) (row-uniform baseline), bf16 -> es ----
  float s2 = 0.f;
  #pragma unroll
  for (int i = 0; i < 16; i++) {
    s16x4 ev;
    #pragma unroll
    for (int r = 0; r < 4; r++) {
      const float e = __expf(acc[i][r] - M2);
      s2 += e;
      ev[r] = (short)f2b(e);
    }
    *(s16x4*)&es[m16][((4 * i + wv) << 4) + (g << 2)] = ev;
  }
  s2 += __shfl_xor(s2, 16); s2 += __shfl_xor(s2, 32);
  if (g == 0) s2p[wv][m16] = s2;
  __syncthreads();

  // ---- GEMM2 (swapped): D[d][m] = cbT . es^T ----
  const float inv2 = 1.0f / (s2p[0][m16] + s2p[1][m16] + s2p[2][m16] + s2p[3][m16]);
  f32x4 qacc = (f32x4){0.f, 0.f, 0.f, 0.f};
  {
    const unsigned short* a2p = cbT16 + (wv * 16 + m16) * K_CB + g * 8;
    const unsigned short* b2p = &es[m16][g * 8];
    #pragma unroll
    for (int kc = 0; kc < 32; kc++) {
      const s16x8 a2 = *(const s16x8*)(a2p + kc * 32);
      const s16x8 b2 = *(const s16x8*)(b2p + kc * 32);
      qacc = __builtin_amdgcn_mfma_f32_16x16x32_bf16(a2, b2, qacc, 0, 0, 0);
    }
  }

  // ---- epilogue: normalize, write, kld_continuous ----
  float kca = 0.f;
  #pragma unroll
  for (int r = 0; r < 4; r++) {
    const int d = wv * 16 + g * 4 + r;
    const int off = ((bidx * D_Z + d) << 10) + rem0 + m16;
    const float qv = qacc[r] * inv2;
    const float xv = x[off];
    out[off] = qv;
    const float dx = xv - qv;
    kca = fmaf(dx, dx, kca);
  }
  #pragma unroll
  for (int off = 1; off < 64; off <<= 1) kca += __shfl_xor(kca, off);
  if (lane == 0) wred[wv] = kca;
  __syncthreads();
  if (tid == 0) {
    float tot = w * (wred[0] + wred[1] + wred[2] + wred[3]);
    #pragma unroll
    for (int i = 0; i < MT; i++) tot += kldrow[i];
    ((float*)(wsb + WS_PART))[blk] = tot;
  }
}

__global__ void vq_reduce(const unsigned char* __restrict__ wsb, float* __restrict__ out) {
  __shared__ float red[256];
  const float* part = (const float*)(wsb + WS_PART);
  const int t = threadIdx.x;
  float s = 0.f;
  for (int i = t; i < NBLK; i += 256) s += part[i];
  red[t] = s;
  __syncthreads();
  for (int st = 128; st > 0; st >>= 1) {
    if (t < st) red[t] += red[t + st];
    __syncthreads();
  }
  if (t == 0) out[NTOT * D_Z] = red[0] * (1.0f / 64.0f);
}

extern "C" void kernel_launch(void* const* d_in, const int* in_sizes, int n_in,
                              void* d_out, int out_size, void* d_ws, size_t ws_size,
                              hipStream_t stream) {
  const float* x   = (const float*)d_in[0];
  const float* cb  = (const float*)d_in[1];
  const float* lvq = (const float*)d_in[2];
  const float* gum = (const float*)d_in[3];
  float* out = (float*)d_out;
  unsigned char* wsb = (unsigned char*)d_ws;

  hipLaunchKernelGGL(vq_prep,   dim3(64),   dim3(256), 0, stream, cb, lvq, wsb);
  hipLaunchKernelGGL(vq_main,   dim3(NBLK), dim3(256), 0, stream, x, gum, lvq, wsb, out);
  hipLaunchKernelGGL(vq_reduce, dim3(1),    dim3(256), 0, stream, wsb, out);
}

// Round 5
// 160.458 us; speedup vs baseline: 1.2016x; 1.0631x over previous
//
#include <hip/hip_runtime.h>
#include <math.h>

#define K_CB 1024
#define D_Z  64
#define MT   32                  // rows per block
#define NTOT 65536
#define NBLK (NTOT / MT)         // 2048

typedef __attribute__((ext_vector_type(8)))  short s16x8;
typedef __attribute__((ext_vector_type(4)))  short s16x4;
typedef __attribute__((ext_vector_type(4)))  float f32x4;
typedef __attribute__((ext_vector_type(16))) float f32x16;

// ws layout (bytes)
#define WS_CB16  0        // [1024][64] bf16
#define WS_CBT16 131072   // [64][1024] bf16
#define WS_NWSQC 262144   // [1024] f32  (-w*||c||^2)
#define WS_PART  266240   // [2048] f32 block partials

__device__ __forceinline__ unsigned short f2b(float f) {
  unsigned int u = __float_as_uint(f);
  u += 0x7fffu + ((u >> 16) & 1u);
  return (unsigned short)(u >> 16);
}

__global__ void vq_prep(const float* __restrict__ cb, const float* __restrict__ lvq,
                        unsigned char* __restrict__ wsb) {
  unsigned short* cb16  = (unsigned short*)(wsb + WS_CB16);
  unsigned short* cbT16 = (unsigned short*)(wsb + WS_CBT16);
  float* nwsqc = (float*)(wsb + WS_NWSQC);
  const float w = 0.5f / fmaxf(1.0f + __expf(lvq[0]), 1e-10f);
  const int tid = threadIdx.x;
  const int k  = blockIdx.x * 16 + (tid >> 4);
  const int d0 = (tid & 15) * 4;
  const f32x4 v = *(const f32x4*)(cb + k * D_Z + d0);
  s16x4 b4;
  #pragma unroll
  for (int i = 0; i < 4; i++) b4[i] = (short)f2b(v[i]);
  *(s16x4*)(cb16 + k * D_Z + d0) = b4;
  #pragma unroll
  for (int i = 0; i < 4; i++) cbT16[(d0 + i) * K_CB + k] = (unsigned short)b4[i];
  float s = v[0]*v[0] + v[1]*v[1] + v[2]*v[2] + v[3]*v[3];
  #pragma unroll
  for (int off = 1; off < 16; off <<= 1) s += __shfl_xor(s, off);
  if ((tid & 15) == 0) nwsqc[k] = -w * s;
}

__global__ __launch_bounds__(512, 4)
void vq_main(const float* __restrict__ x, const float* __restrict__ gum,
             const float* __restrict__ lvq, unsigned char* __restrict__ wsb,
             float* __restrict__ out) {
  // LDS: 4096 + 65536 + 4096 + 1024 + 128 + 32 = 70912 B -> 2 blocks/CU
  __shared__ __align__(16) unsigned short xa[MT * D_Z];   // XOR-swizzled [m][d]
  __shared__ __align__(16) unsigned short es[MT * K_CB];  // XOR-swizzled [m][k]
  __shared__ __align__(16) float stats[8][MT][4];         // m1,s1,A,m2 per wave/row
  __shared__ __align__(16) float s2s[8][MT];
  __shared__ float kldrow[MT];
  __shared__ float wred[8];

  const int tid  = threadIdx.x;
  const int w    = tid >> 6;           // wave 0..7, owns codes [w*128, +128)
  const int lane = tid & 63;
  const int m32  = lane & 31;          // output row (MFMA col)
  const int hi   = lane >> 5;
  const int bid  = blockIdx.x;
  const int blk  = ((bid & 7) << 8) | (bid >> 3);   // bijective XCD remap (2048=8*256)
  const int row0 = blk * MT;
  const int bidx = row0 >> 10;
  const int rem0 = row0 & 1023;
  const int kw0  = w << 7;

  const float wq = 0.5f / fmaxf(1.0f + __expf(lvq[0]), 1e-10f);
  const float w2 = 2.0f * wq;

  const unsigned short* cb16  = (const unsigned short*)(wsb + WS_CB16);
  const unsigned short* cbT16 = (const unsigned short*)(wsb + WS_CBT16);
  const float* nwsqc = (const float*)(wsb + WS_NWSQC);

  // ---- P0: stage x tile [32 rows][64 d] bf16, XOR-swizzled rows ----
  {
    const int m = tid & 31, dg = tid >> 5;   // dg 0..15
    #pragma unroll
    for (int i = 0; i < 4; i++) {
      const int d = dg + 16 * i;
      const float v = x[((bidx * D_Z + d) << 10) + rem0 + m];
      xa[(m * D_Z + d) ^ ((m & 7) << 3)] = f2b(v);
    }
  }
  __syncthreads();

  // ---- GEMM1 (swapped, 32x32x16): D[code][m], wave codes kw0..+128 ----
  f32x16 acc[4];
  #pragma unroll
  for (int t = 0; t < 4; t++)
    #pragma unroll
    for (int r = 0; r < 16; r++) acc[t][r] = 0.f;
  {
    s16x8 bx[4];
    #pragma unroll
    for (int kb = 0; kb < 4; kb++) {
      const int byteoff = (m32 * 128 + kb * 32 + hi * 16) ^ ((m32 & 7) << 4);
      bx[kb] = *(const s16x8*)((const unsigned char*)xa + byteoff);
    }
    #pragma unroll
    for (int t = 0; t < 4; t++) {
      const unsigned short* ap = cb16 + (kw0 + t * 32 + m32) * D_Z + hi * 8;
      #pragma unroll
      for (int kb = 0; kb < 4; kb++) {
        const s16x8 a = *(const s16x8*)(ap + kb * 16);
        acc[t] = __builtin_amdgcn_mfma_f32_32x32x16_bf16(a, bx[kb], acc[t], 0, 0, 0);
      }
    }
  }

  // ---- logits: acc = w2*cross + (-w*||c||^2); per-wave row max m1 ----
  float m1 = -3.4e38f;
  #pragma unroll
  for (int t = 0; t < 4; t++) {
    #pragma unroll
    for (int q = 0; q < 4; q++) {
      const f32x4 nw = *(const f32x4*)(nwsqc + kw0 + t * 32 + q * 8 + hi * 4);
      #pragma unroll
      for (int i = 0; i < 4; i++) {
        acc[t][q * 4 + i] = fmaf(w2, acc[t][q * 4 + i], nw[i]);
        m1 = fmaxf(m1, acc[t][q * 4 + i]);
      }
    }
  }
  m1 = fmaxf(m1, __shfl_xor(m1, 32));

  // ---- issue gumbel batch A (tiles 0,1) ----
  const float* gp = gum + ((size_t)(row0 + m32) << 10) + kw0 + hi * 4;
  f32x4 gA[8];
  #pragma unroll
  for (int u = 0; u < 8; u++)
    gA[u] = *(const f32x4*)(gp + (u >> 2) * 32 + (u & 3) * 8);

  // ---- s1 / A pass (hides gA latency) ----
  float s1 = 0.f, Aa = 0.f;
  #pragma unroll
  for (int t = 0; t < 4; t++) {
    #pragma unroll
    for (int r = 0; r < 16; r++) {
      const float u = acc[t][r] - m1;
      const float e = __expf(u);
      s1 += e;
      Aa = fmaf(u, e, Aa);
    }
  }
  s1 += __shfl_xor(s1, 32);
  Aa += __shfl_xor(Aa, 32);

  // ---- z = 2*(logit+g): tiles 0,1; issue batch B; tiles 2,3; per-wave m2 ----
  float m2 = -3.4e38f;
  #pragma unroll
  for (int u = 0; u < 8; u++) {
    const int t = u >> 2, q = u & 3;
    #pragma unroll
    for (int i = 0; i < 4; i++) {
      const float z = 2.0f * (acc[t][q * 4 + i] + gA[u][i]);
      acc[t][q * 4 + i] = z;
      m2 = fmaxf(m2, z);
    }
  }
  f32x4 gB[8];
  #pragma unroll
  for (int u = 0; u < 8; u++)
    gB[u] = *(const f32x4*)(gp + 64 + (u >> 2) * 32 + (u & 3) * 8);
  #pragma unroll
  for (int u = 0; u < 8; u++) {
    const int t = 2 + (u >> 2), q = u & 3;
    #pragma unroll
    for (int i = 0; i < 4; i++) {
      const float z = 2.0f * (acc[t][q * 4 + i] + gB[u][i]);
      acc[t][q * 4 + i] = z;
      m2 = fmaxf(m2, z);
    }
  }
  m2 = fmaxf(m2, __shfl_xor(m2, 32));
  if (hi == 0) {
    f32x4 st = {m1, s1, Aa, m2};
    *(f32x4*)&stats[w][m32][0] = st;
  }
  __syncthreads();

  // ---- cross-wave: global row max M2; wave 0 computes kld_discrete rows ----
  float M2 = -3.4e38f;
  {
    f32x4 st[8];
    #pragma unroll
    for (int q = 0; q < 8; q++) {
      st[q] = *(const f32x4*)&stats[q][m32][0];
      M2 = fmaxf(M2, st[q][3]);
    }
    if (w == 0) {
      float M1 = -3.4e38f;
      #pragma unroll
      for (int q = 0; q < 8; q++) M1 = fmaxf(M1, st[q][0]);
      float s1g = 0.f, Ag = 0.f;
      #pragma unroll
      for (int q = 0; q < 8; q++) {
        const float dm = st[q][0] - M1;
        const float c  = __expf(dm);
        s1g += c * st[q][1];
        Ag = fmaf(c, fmaf(dm, st[q][1], st[q][2]), Ag);
      }
      if (hi == 0) kldrow[m32] = Ag / s1g - __logf(s1g);
    }
  }

  // ---- encode e = exp(z - M2) (row-global baseline), bf16 pairs -> es ----
  float s2 = 0.f;
  #pragma unroll
  for (int t = 0; t < 4; t++) {
    #pragma unroll
    for (int q = 0; q < 4; q++) {
      float e[4];
      #pragma unroll
      for (int i = 0; i < 4; i++) {
        e[i] = __expf(acc[t][q * 4 + i] - M2);
        s2 += e[i];
      }
      const unsigned int p0 = (unsigned int)f2b(e[0]) | ((unsigned int)f2b(e[1]) << 16);
      const unsigned int p1 = (unsigned int)f2b(e[2]) | ((unsigned int)f2b(e[3]) << 16);
      const unsigned long long pk = (unsigned long long)p0 | ((unsigned long long)p1 << 32);
      const int byteoff = (m32 * 2048 + (kw0 + t * 32 + q * 8 + hi * 4) * 2) ^ ((m32 & 7) << 4);
      *(unsigned long long*)((unsigned char*)es + byteoff) = pk;
    }
  }
  s2 += __shfl_xor(s2, 32);
  if (hi == 0) s2s[w][m32] = s2;
  __syncthreads();

  // ---- GEMM2 (swapped, 16x16x32): wave -> tile (d-block w>>1, m-block w&1) ----
  const int m16 = lane & 15, g = lane >> 4;
  const int db = w >> 1, mb = w & 1;
  const int mrow = mb * 16 + m16;
  float s2g = 0.f;
  #pragma unroll
  for (int q = 0; q < 8; q++) s2g += s2s[q][mrow];
  const float inv2 = 1.0f / s2g;

  f32x4 qacc = (f32x4){0.f, 0.f, 0.f, 0.f};
  {
    const unsigned short* a2p = cbT16 + (db * 16 + m16) * K_CB + g * 8;
    const unsigned char* esb = (const unsigned char*)es;
    #pragma unroll
    for (int kc = 0; kc < 32; kc++) {
      const s16x8 a2 = *(const s16x8*)(a2p + kc * 32);
      const int byteoff = (mrow * 2048 + kc * 64 + g * 16) ^ ((m16 & 7) << 4);
      const s16x8 b2 = *(const s16x8*)(esb + byteoff);
      qacc = __builtin_amdgcn_mfma_f32_16x16x32_bf16(a2, b2, qacc, 0, 0, 0);
    }
  }

  // ---- epilogue: normalize, write, kld_continuous ----
  float kca = 0.f;
  #pragma unroll
  for (int r = 0; r < 4; r++) {
    const int d = db * 16 + g * 4 + r;
    const int off = ((bidx * D_Z + d) << 10) + rem0 + mrow;
    const float qv = qacc[r] * inv2;
    const float xv = x[off];
    out[off] = qv;
    const float dx = xv - qv;
    kca = fmaf(dx, dx, kca);
  }
  #pragma unroll
  for (int off = 1; off < 64; off <<= 1) kca += __shfl_xor(kca, off);
  if (lane == 0) wred[w] = kca;
  __syncthreads();
  if (tid == 0) {
    float tot = 0.f;
    #pragma unroll
    for (int q = 0; q < 8; q++) tot += wred[q];
    tot *= wq;
    #pragma unroll
    for (int i = 0; i < MT; i++) tot += kldrow[i];
    ((float*)(wsb + WS_PART))[blk] = tot;
  }
}

__global__ void vq_reduce(const unsigned char* __restrict__ wsb, float* __restrict__ out) {
  __shared__ float red[256];
  const float* part = (const float*)(wsb + WS_PART);
  const int t = threadIdx.x;
  float s = 0.f;
  for (int i = t; i < NBLK; i += 256) s += part[i];
  red[t] = s;
  __syncthreads();
  for (int st = 128; st > 0; st >>= 1) {
    if (t < st) red[t] += red[t + st];
    __syncthreads();
  }
  if (t == 0) out[NTOT * D_Z] = red[0] * (1.0f / 64.0f);
}

extern "C" void kernel_launch(void* const* d_in, const int* in_sizes, int n_in,
                              void* d_out, int out_size, void* d_ws, size_t ws_size,
                              hipStream_t stream) {
  const float* x   = (const float*)d_in[0];
  const float* cb  = (const float*)d_in[1];
  const float* lvq = (const float*)d_in[2];
  const float* gum = (const float*)d_in[3];
  float* out = (float*)d_out;
  unsigned char* wsb = (unsigned char*)d_ws;

  hipLaunchKernelGGL(vq_prep,   dim3(64),   dim3(256), 0, stream, cb, lvq, wsb);
  hipLaunchKernelGGL(vq_main,   dim3(NBLK), dim3(512), 0, stream, x, gum, lvq, wsb, out);
  hipLaunchKernelGGL(vq_reduce, dim3(1),    dim3(256), 0, stream, wsb, out);
}